// Round 1
// baseline (1380.893 us; speedup 1.0000x reference)
//
#include <hip/hip_runtime.h>
#include <hip/hip_bf16.h>
#include <cstdint>

#define B_SZ 1000
#define D_SZ 512
#define N_SZ 100000
#define F_SZ 50
#define NEGV -1000000.0f

#define BM 128
#define BN 128
#define BK 32
#define NT_N 782   // ceil(100000/128)
#define NT_B 8     // ceil(1000/128)
#define CAP 64

#define T_OFF 0
#define CNT_OFF 4096
#define ENT_OFF 32768

typedef __bf16 bf16x8 __attribute__((ext_vector_type(8)));
typedef __bf16 bf16x4 __attribute__((ext_vector_type(4)));
typedef float f32x4 __attribute__((ext_vector_type(4)));

// ---------------- zero the t/cnt regions of ws (poisoned 0xAA each call) ----
__global__ void zero_ws(int* p){ p[blockIdx.x * 256 + threadIdx.x] = 0; }

// ---------------- t[b] = q[b] . rhs[:, target[b]] (f32 exact) --------------
__global__ void t_kernel(const float* __restrict__ q, const float* __restrict__ rhs,
                         const int* __restrict__ target, float* __restrict__ t){
  int b = blockIdx.x;
  int tid = threadIdx.x;
  int tj = target[b];
  const float* qb = q + (size_t)b * D_SZ;
  float p = qb[tid] * rhs[(size_t)tid * N_SZ + tj]
          + qb[tid + 256] * rhs[(size_t)(tid + 256) * N_SZ + tj];
  for(int off = 32; off; off >>= 1) p += __shfl_down(p, off);
  __shared__ float red[4];
  if((tid & 63) == 0) red[tid >> 6] = p;
  __syncthreads();
  if(tid == 0) t[b] = red[0] + red[1] + red[2] + red[3];
}

// ---------------- dedupe filter∪target, bin into owning GEMM block ---------
__global__ void prep_kernel(const int* __restrict__ filt, const int* __restrict__ target,
                            const float* __restrict__ t, int* __restrict__ cnt,
                            unsigned* __restrict__ entries, float* __restrict__ out){
  int b = blockIdx.x * blockDim.x + threadIdx.x;
  if(b >= B_SZ) return;
  int idx[F_SZ + 1];
  for(int i = 0; i < F_SZ; i++) idx[i] = filt[b * F_SZ + i];
  idx[F_SZ] = target[b];
  float tb = t[b];
  int nuniq = 0;
  for(int i = 0; i <= F_SZ; i++){
    int j = idx[i];
    bool first = true;
    for(int k = 0; k < i; k++) if(idx[k] == j){ first = false; break; }
    if(!first) continue;
    nuniq++;
    int bid = (b >> 7) * NT_N + (j >> 7);
    int pos = atomicAdd(&cnt[bid], 1);
    if(pos < CAP)
      entries[(size_t)bid * CAP + pos] = (unsigned)(((b & 127) << 7) | (j & 127));
  }
  // rank base: 1 + (each unique filtered col contributes [NEG >= t])
  out[b] = 1.0f + ((NEGV >= tb) ? (float)nuniq : 0.0f);
}

// ---------------- fused bf16 MFMA GEMM + rank count ------------------------
__global__ __launch_bounds__(256)
void main_kernel(const float* __restrict__ q, const float* __restrict__ rhs,
                 const float* __restrict__ t, const int* __restrict__ cnt,
                 const unsigned* __restrict__ entries, float* __restrict__ out){
  // A: [m][k], stride 40 (pad 8): b128 frag reads 16B-aligned, 2-way banks (free)
  // B: [n][k], stride 36 (pad 4): rotated b64 writes conflict-free; frag reads 2xb64
  __shared__ __bf16 Ab[BM][40];
  __shared__ __bf16 Bb[BN][36];
  __shared__ float tl[BM];
  __shared__ unsigned lent[CAP];
  __shared__ int lcnt_s;

  const int tile_n = blockIdx.x;
  const int tile_b = blockIdx.y;
  const int bid = tile_b * NT_N + tile_n;
  const int tid = threadIdx.x;
  const int n0 = tile_n * BN;
  const int b0 = tile_b * BM;

  if(tid < BM){
    int b = b0 + tid;
    tl[tid] = (b < B_SZ) ? t[b] : 0.0f;
  }
  if(tid == 0){
    int c = cnt[bid];
    lcnt_s = (c > CAP) ? CAP : c;
  }
  if(tid < CAP) lent[tid] = entries[(size_t)bid * CAP + tid];

  f32x4 acc[4][4];
  #pragma unroll
  for(int i = 0; i < 4; i++)
    #pragma unroll
    for(int j = 0; j < 4; j++)
      acc[i][j] = (f32x4){0.f, 0.f, 0.f, 0.f};

  const int lane = tid & 63;
  const int quad = lane >> 4;
  const int l15  = lane & 15;
  const int wave = tid >> 6;
  const int wr0 = (wave >> 1) * 64;
  const int wc0 = (wave & 1) * 64;

  // A staging: thread covers row=tid>>1, k-range ad0..ad0+15
  const int arow = tid >> 1;
  const int ad0  = (tid & 1) * 16;
  const bool aok = (b0 + arow) < B_SZ;
  const float* aptr = q + (size_t)(b0 + arow) * D_SZ + ad0;

  // B staging: thread covers 4 k-rows (dblk*4..+3) x 4 n-cols (nblk*4..+3)
  const int dblk = tid >> 5;   // 0..7
  const int nblk = tid & 31;   // 0..31
  const int nga = n0 + nblk * 4;
  const float* bptr = rhs + (size_t)(dblk * 4) * N_SZ + nga;

  for(int kk = 0; kk < D_SZ; kk += BK){
    __syncthreads();
    // ---- stage A (f32 -> bf16) ----
    {
      float va[16];
      #pragma unroll
      for(int i = 0; i < 4; i++){
        float4 v = aok ? *(const float4*)(aptr + kk + i * 4) : make_float4(0.f, 0.f, 0.f, 0.f);
        va[i*4+0] = v.x; va[i*4+1] = v.y; va[i*4+2] = v.z; va[i*4+3] = v.w;
      }
      bf16x8 w0, w1;
      #pragma unroll
      for(int k = 0; k < 8; k++){ w0[k] = (__bf16)va[k]; w1[k] = (__bf16)va[8 + k]; }
      *(bf16x8*)&Ab[arow][ad0]     = w0;
      *(bf16x8*)&Ab[arow][ad0 + 8] = w1;
    }
    // ---- stage B (f32 -> bf16, transpose to [n][k]) ----
    {
      float vv[4][4];
      const float* p = bptr + (size_t)kk * N_SZ;
      #pragma unroll
      for(int i = 0; i < 4; i++){
        if(nga + 3 < N_SZ){
          float4 v = *(const float4*)(p + (size_t)i * N_SZ);
          vv[i][0] = v.x; vv[i][1] = v.y; vv[i][2] = v.z; vv[i][3] = v.w;
        } else {
          #pragma unroll
          for(int c = 0; c < 4; c++)
            vv[i][c] = (nga + c < N_SZ) ? p[(size_t)i * N_SZ + c] : 0.f;
        }
      }
      #pragma unroll
      for(int cc = 0; cc < 4; cc++){
        int c = (cc + (nblk >> 2)) & 3;   // rotate write order: kills bank conflicts
        bf16x4 w = { (__bf16)vv[0][c], (__bf16)vv[1][c], (__bf16)vv[2][c], (__bf16)vv[3][c] };
        *(bf16x4*)&Bb[nblk * 4 + c][dblk * 4] = w;
      }
    }
    __syncthreads();
    // ---- fragments + MFMA ----
    bf16x8 af[4], bfr[4];
    #pragma unroll
    for(int i = 0; i < 4; i++)
      af[i] = *(bf16x8*)&Ab[wr0 + i * 16 + l15][quad * 8];
    #pragma unroll
    for(int j = 0; j < 4; j++){
      bf16x4 lo = *(bf16x4*)&Bb[wc0 + j * 16 + l15][quad * 8];
      bf16x4 hi = *(bf16x4*)&Bb[wc0 + j * 16 + l15][quad * 8 + 4];
      bfr[j] = __builtin_shufflevector(lo, hi, 0, 1, 2, 3, 4, 5, 6, 7);
    }
    #pragma unroll
    for(int i = 0; i < 4; i++)
      #pragma unroll
      for(int j = 0; j < 4; j++)
        acc[i][j] = __builtin_amdgcn_mfma_f32_16x16x32_bf16(af[i], bfr[j], acc[i][j], 0, 0, 0);
  }

  // ---- epilogue: count s >= t_b ----
  // C/D layout (verified m89/m91): col = lane&15, row = quad*4 + reg
  int cntv[4][4];
  #pragma unroll
  for(int rt = 0; rt < 4; rt++){
    #pragma unroll
    for(int r = 0; r < 4; r++){
      int row = wr0 + rt * 16 + quad * 4 + r;
      float trow = tl[row];
      int c = 0;
      #pragma unroll
      for(int ct = 0; ct < 4; ct++){
        int ncol = n0 + wc0 + ct * 16 + l15;
        if(ncol < N_SZ && acc[rt][ct][r] >= trow) c++;
      }
      cntv[rt][r] = c;
    }
  }

  // ---- subtract filtered entries owned by this block ----
  int lc = lcnt_s;
  for(int e = 0; e < lc; e++){
    unsigned en = lent[e];
    int row = en >> 7;
    int col = en & 127;
    int rr = row - wr0;
    int ccl = col - wc0;
    if(rr >= 0 && rr < 64 && ccl >= 0 && ccl < 64 &&
       quad == ((rr & 15) >> 2) && l15 == (ccl & 15)){
      int rt = rr >> 4, ct = ccl >> 4, r = rr & 3;
      float trow = tl[row];
      #pragma unroll
      for(int i = 0; i < 4; i++)
        #pragma unroll
        for(int j = 0; j < 4; j++)
          #pragma unroll
          for(int k = 0; k < 4; k++)
            if(i == rt && j == ct && k == r && acc[i][j][k] >= trow)
              cntv[i][k]--;
    }
  }

  // ---- reduce across the 16 lanes of each quad (cols), atomic per row ----
  #pragma unroll
  for(int rt = 0; rt < 4; rt++){
    #pragma unroll
    for(int r = 0; r < 4; r++){
      int c = cntv[rt][r];
      c += __shfl_xor(c, 1);
      c += __shfl_xor(c, 2);
      c += __shfl_xor(c, 4);
      c += __shfl_xor(c, 8);
      if(l15 == 0){
        int bg = b0 + wr0 + rt * 16 + quad * 4 + r;
        if(bg < B_SZ) atomicAdd(&out[bg], (float)c);
      }
    }
  }
}

extern "C" void kernel_launch(void* const* d_in, const int* in_sizes, int n_in,
                              void* d_out, int out_size, void* d_ws, size_t ws_size,
                              hipStream_t stream){
  const float* q    = (const float*)d_in[0];
  const float* rhs  = (const float*)d_in[1];
  const int* filt   = (const int*)d_in[2];
  const int* target = (const int*)d_in[3];
  float* out = (float*)d_out;
  char* ws = (char*)d_ws;
  float* t          = (float*)(ws + T_OFF);
  int* cnt          = (int*)(ws + CNT_OFF);
  unsigned* entries = (unsigned*)(ws + ENT_OFF);
  // ws usage: 32768 + 782*8*64*4 = ~1.6 MB

  zero_ws<<<32, 256, 0, stream>>>((int*)ws);                       // t + cnt regions
  t_kernel<<<B_SZ, 256, 0, stream>>>(q, rhs, target, t);
  prep_kernel<<<(B_SZ + 255) / 256, 256, 0, stream>>>(filt, target, t, cnt, entries, out);
  dim3 grid(NT_N, NT_B);
  main_kernel<<<grid, 256, 0, stream>>>(q, rhs, t, cnt, entries, out);
}

// Round 2
// 996.172 us; speedup vs baseline: 1.3862x; 1.3862x over previous
//
#include <hip/hip_runtime.h>
#include <hip/hip_bf16.h>
#include <cstdint>

#define B_SZ 1000
#define D_SZ 512
#define N_SZ 100000
#define F_SZ 50
#define NEGV -1000000.0f

#define BM 128
#define BN 128
#define BK 32
#define NT_N 782   // ceil(100000/128)
#define NT_B 8     // ceil(1000/128)
#define CAP 64

#define T_OFF 0
#define CNT_OFF 4096
#define ENT_OFF 32768

typedef __bf16 bf16x8 __attribute__((ext_vector_type(8)));
typedef __bf16 bf16x4 __attribute__((ext_vector_type(4)));
typedef float f32x4 __attribute__((ext_vector_type(4)));

// ---------------- zero the t/cnt regions of ws (poisoned 0xAA each call) ----
__global__ void zero_ws(int* p){ p[blockIdx.x * 256 + threadIdx.x] = 0; }

// ---------------- t[b] = q[b] . rhs[:, target[b]] (f32 exact) --------------
__global__ void t_kernel(const float* __restrict__ q, const float* __restrict__ rhs,
                         const int* __restrict__ target, float* __restrict__ t){
  int b = blockIdx.x;
  int tid = threadIdx.x;
  int tj = target[b];
  const float* qb = q + (size_t)b * D_SZ;
  float p = qb[tid] * rhs[(size_t)tid * N_SZ + tj]
          + qb[tid + 256] * rhs[(size_t)(tid + 256) * N_SZ + tj];
  for(int off = 32; off; off >>= 1) p += __shfl_down(p, off);
  __shared__ float red[4];
  if((tid & 63) == 0) red[tid >> 6] = p;
  __syncthreads();
  if(tid == 0) t[b] = red[0] + red[1] + red[2] + red[3];
}

// ---------------- dedupe filter∪target, bin into owning GEMM block ---------
__global__ void prep_kernel(const int* __restrict__ filt, const int* __restrict__ target,
                            const float* __restrict__ t, int* __restrict__ cnt,
                            unsigned* __restrict__ entries, float* __restrict__ out){
  int b = blockIdx.x * blockDim.x + threadIdx.x;
  if(b >= B_SZ) return;
  int idx[F_SZ + 1];
  for(int i = 0; i < F_SZ; i++) idx[i] = filt[b * F_SZ + i];
  idx[F_SZ] = target[b];
  float tb = t[b];
  int nuniq = 0;
  for(int i = 0; i <= F_SZ; i++){
    int j = idx[i];
    bool first = true;
    for(int k = 0; k < i; k++) if(idx[k] == j){ first = false; break; }
    if(!first) continue;
    nuniq++;
    int bid = (b >> 7) * NT_N + (j >> 7);
    int pos = atomicAdd(&cnt[bid], 1);
    if(pos < CAP)
      entries[(size_t)bid * CAP + pos] = (unsigned)(((b & 127) << 7) | (j & 127));
  }
  // rank base: 1 + (each unique filtered col contributes [NEG >= t])
  out[b] = 1.0f + ((NEGV >= tb) ? (float)nuniq : 0.0f);
}

// ---------------- fused bf16 MFMA GEMM + rank count ------------------------
__global__ __launch_bounds__(256)
void main_kernel(const float* __restrict__ q, const float* __restrict__ rhs,
                 const float* __restrict__ t, const int* __restrict__ cnt,
                 const unsigned* __restrict__ entries, float* __restrict__ out){
  // A: [m][k], stride 40 (pad 8): b128 frag reads 16B-aligned, 2-way banks (free)
  // B: [n][k], stride 36 (pad 4): rotated b64 writes conflict-free; frag reads 2xb64
  __shared__ __bf16 Ab[BM][40];
  __shared__ __bf16 Bb[BN][36];
  __shared__ float tl[BM];
  __shared__ unsigned lent[CAP];
  __shared__ int lcnt_s;

  // grid swapped: b-tile fastest -> the 8 blocks sharing a B-strip are
  // dispatched consecutively (different XCDs) -> LLC/L2 absorbs rhs re-reads
  const int tile_b = blockIdx.x;
  const int tile_n = blockIdx.y;
  const int bid = tile_b * NT_N + tile_n;
  const int tid = threadIdx.x;
  const int n0 = tile_n * BN;
  const int b0 = tile_b * BM;

  if(tid < BM){
    int b = b0 + tid;
    tl[tid] = (b < B_SZ) ? t[b] : 0.0f;
  }
  if(tid == 0){
    int c = cnt[bid];
    lcnt_s = (c > CAP) ? CAP : c;
  }
  if(tid < CAP) lent[tid] = entries[(size_t)bid * CAP + tid];

  f32x4 acc[4][4];
  #pragma unroll
  for(int i = 0; i < 4; i++)
    #pragma unroll
    for(int j = 0; j < 4; j++)
      acc[i][j] = (f32x4){0.f, 0.f, 0.f, 0.f};

  const int lane = tid & 63;
  const int quad = lane >> 4;
  const int l15  = lane & 15;
  const int wave = tid >> 6;
  const int wr0 = (wave >> 1) * 64;
  const int wc0 = (wave & 1) * 64;

  // A staging: thread covers row=tid>>1, k-range ad0..ad0+15
  const int arow = tid >> 1;
  const int ad0  = (tid & 1) * 16;
  const bool aok = (b0 + arow) < B_SZ;
  const float* aptr = q + (size_t)(b0 + arow) * D_SZ + ad0;

  // B staging: thread covers 4 k-rows (dblk*4..+3) x 4 n-cols (nblk*4..+3)
  const int dblk = tid >> 5;   // 0..7
  const int nblk = tid & 31;   // 0..31
  const int nga = n0 + nblk * 4;
  const bool bok = (nga + 3) < N_SZ;   // N%4==0 so tiles are all-in or all-out
  const float* bptr = rhs + (size_t)(dblk * 4) * N_SZ + nga;

  // ---- software pipeline: prefetch k-chunk into registers ----
  float va[16];
  float vb[16];   // vb[i*4+c] = B[k=dblk*4+i][n=nga+c]

  #define LOAD_A(KK) do { \
    _Pragma("unroll") \
    for(int i = 0; i < 4; i++){ \
      float4 v = aok ? *(const float4*)(aptr + (KK) + i * 4) : make_float4(0.f,0.f,0.f,0.f); \
      va[i*4+0]=v.x; va[i*4+1]=v.y; va[i*4+2]=v.z; va[i*4+3]=v.w; \
    } } while(0)
  #define LOAD_B(KK) do { \
    const float* p_ = bptr + (size_t)(KK) * N_SZ; \
    _Pragma("unroll") \
    for(int i = 0; i < 4; i++){ \
      float4 v = bok ? *(const float4*)(p_ + (size_t)i * N_SZ) : make_float4(0.f,0.f,0.f,0.f); \
      vb[i*4+0]=v.x; vb[i*4+1]=v.y; vb[i*4+2]=v.z; vb[i*4+3]=v.w; \
    } } while(0)

  LOAD_A(0);
  LOAD_B(0);

  for(int kk = 0; kk < D_SZ; kk += BK){
    // ---- stage registers -> LDS (f32 -> bf16) ----
    {
      bf16x8 w0, w1;
      #pragma unroll
      for(int k = 0; k < 8; k++){ w0[k] = (__bf16)va[k]; w1[k] = (__bf16)va[8 + k]; }
      *(bf16x8*)&Ab[arow][ad0]     = w0;
      *(bf16x8*)&Ab[arow][ad0 + 8] = w1;
    }
    {
      #pragma unroll
      for(int cc = 0; cc < 4; cc++){
        int c = (cc + (nblk >> 2)) & 3;   // rotate write order: kills bank conflicts
        bf16x4 w = { (__bf16)vb[0*4+c], (__bf16)vb[1*4+c], (__bf16)vb[2*4+c], (__bf16)vb[3*4+c] };
        *(bf16x4*)&Bb[nblk * 4 + c][dblk * 4] = w;
      }
    }
    __syncthreads();

    // ---- prefetch next chunk (waited only at next iteration's stage) ----
    if(kk + BK < D_SZ){
      LOAD_A(kk + BK);
      LOAD_B(kk + BK);
    }

    // ---- fragments + MFMA (overlaps the in-flight prefetch) ----
    bf16x8 af[4], bfr[4];
    #pragma unroll
    for(int i = 0; i < 4; i++)
      af[i] = *(bf16x8*)&Ab[wr0 + i * 16 + l15][quad * 8];
    #pragma unroll
    for(int j = 0; j < 4; j++){
      bf16x4 lo = *(bf16x4*)&Bb[wc0 + j * 16 + l15][quad * 8];
      bf16x4 hi = *(bf16x4*)&Bb[wc0 + j * 16 + l15][quad * 8 + 4];
      bfr[j] = __builtin_shufflevector(lo, hi, 0, 1, 2, 3, 4, 5, 6, 7);
    }
    #pragma unroll
    for(int i = 0; i < 4; i++)
      #pragma unroll
      for(int j = 0; j < 4; j++)
        acc[i][j] = __builtin_amdgcn_mfma_f32_16x16x32_bf16(af[i], bfr[j], acc[i][j], 0, 0, 0);

    __syncthreads();   // frag reads done before next stage overwrites LDS
  }

  // ---- epilogue: count s >= t_b ----
  // C/D layout (verified m89/m91): col = lane&15, row = quad*4 + reg
  int cntv[4][4];
  #pragma unroll
  for(int rt = 0; rt < 4; rt++){
    #pragma unroll
    for(int r = 0; r < 4; r++){
      int row = wr0 + rt * 16 + quad * 4 + r;
      float trow = tl[row];
      int c = 0;
      #pragma unroll
      for(int ct = 0; ct < 4; ct++){
        int ncol = n0 + wc0 + ct * 16 + l15;
        if(ncol < N_SZ && acc[rt][ct][r] >= trow) c++;
      }
      cntv[rt][r] = c;
    }
  }

  // ---- subtract filtered entries owned by this block ----
  int lc = lcnt_s;
  for(int e = 0; e < lc; e++){
    unsigned en = lent[e];
    int row = en >> 7;
    int col = en & 127;
    int rr = row - wr0;
    int ccl = col - wc0;
    if(rr >= 0 && rr < 64 && ccl >= 0 && ccl < 64 &&
       quad == ((rr & 15) >> 2) && l15 == (ccl & 15)){
      int rt = rr >> 4, ct = ccl >> 4, r = rr & 3;
      float trow = tl[row];
      #pragma unroll
      for(int i = 0; i < 4; i++)
        #pragma unroll
        for(int j = 0; j < 4; j++)
          #pragma unroll
          for(int k = 0; k < 4; k++)
            if(i == rt && j == ct && k == r && acc[i][j][k] >= trow)
              cntv[i][k]--;
    }
  }

  // ---- reduce across the 16 lanes of each quad (cols), atomic per row ----
  #pragma unroll
  for(int rt = 0; rt < 4; rt++){
    #pragma unroll
    for(int r = 0; r < 4; r++){
      int c = cntv[rt][r];
      c += __shfl_xor(c, 1);
      c += __shfl_xor(c, 2);
      c += __shfl_xor(c, 4);
      c += __shfl_xor(c, 8);
      if(l15 == 0){
        int bg = b0 + wr0 + rt * 16 + quad * 4 + r;
        if(bg < B_SZ) atomicAdd(&out[bg], (float)c);
      }
    }
  }
}

extern "C" void kernel_launch(void* const* d_in, const int* in_sizes, int n_in,
                              void* d_out, int out_size, void* d_ws, size_t ws_size,
                              hipStream_t stream){
  const float* q    = (const float*)d_in[0];
  const float* rhs  = (const float*)d_in[1];
  const int* filt   = (const int*)d_in[2];
  const int* target = (const int*)d_in[3];
  float* out = (float*)d_out;
  char* ws = (char*)d_ws;
  float* t          = (float*)(ws + T_OFF);
  int* cnt          = (int*)(ws + CNT_OFF);
  unsigned* entries = (unsigned*)(ws + ENT_OFF);
  // ws usage: 32768 + 782*8*64*4 = ~1.6 MB

  zero_ws<<<32, 256, 0, stream>>>((int*)ws);                       // t + cnt regions
  t_kernel<<<B_SZ, 256, 0, stream>>>(q, rhs, target, t);
  prep_kernel<<<(B_SZ + 255) / 256, 256, 0, stream>>>(filt, target, t, cnt, entries, out);
  dim3 grid(NT_B, NT_N);   // b-tile fastest for B-strip L2/LLC locality
  main_kernel<<<grid, 256, 0, stream>>>(q, rhs, t, cnt, entries, out);
}